// Round 1
// baseline (88.338 us; speedup 1.0000x reference)
//
#include <hip/hip_runtime.h>
#include <math.h>
#include <stdint.h>

constexpr int NSEG = 128;
constexpr int P    = 512;
constexpr int D    = 64;
constexpr int KT   = 15;
constexpr int NCLS = 8;

// ---------------- workspace layout ----------------
// [0, 256 KB)   : dist (NSEG*P floats) -- written phase A, read by combine
// at +1 MiB     : control block (zeroed by a tiny hipMemsetAsync each launch,
//                 so no assumptions about the harness's ws poison value):
//   qcnt[seg] @ u32 index seg*16   (64 B stride to dodge any fill-pattern
//                                   aliasing and atomic line contention)
//   ccnt      @ u32 index NSEG*16
//   partial[] @ u32 index (NSEG+2)*16  (written-before-read, no init needed)
constexpr size_t CTRL_OFF = (size_t)1 << 20;
constexpr size_t CTRL_ZERO_BYTES = (NSEG * 16 + 16) * sizeof(uint32_t); // qcnt+ccnt

// One fused kernel, 2 blocks per segment (256 blocks x 512 threads = full
// device for the BW phase). Per segment, the second of its two blocks to
// finish phase A (elected via agent-scope fetch_add on qcnt[seg]) runs the
// combine phase immediately -- no global barrier, no second full launch.
// The 128th combine block (elected via ccnt) does the deterministic final
// sum and is the single writer of out[0].
// Per-segment arithmetic is verbatim from the previous passing version
// (same shuffle trees / selection order -> bit-identical per-segment sums).
__global__ __launch_bounds__(512, 1) void lmnn_fused(
    const float* __restrict__ center,   // (NSEG, D)
    const float* __restrict__ outputs,  // (NSEG, P, D)
    const int*   __restrict__ labels,   // (NSEG, P)
    float* __restrict__ ws,
    float* __restrict__ out)            // scalar, written once by final block
{
    __shared__ float s_dist[P];
    __shared__ int   s_lab[P];
    __shared__ float s_S[NCLS];
    __shared__ float s_M[NCLS];
    __shared__ int   s_cnt[NCLS];
    __shared__ float s_hb[NCLS];   // 1 + M[c]
    __shared__ float s_dc[NCLS];   // P - cnt[c]
    __shared__ float s_margin;
    __shared__ float s_pull;
    __shared__ float s_wsum[8];
    __shared__ int   s_flag;

    const int bid  = blockIdx.x;     // 0 .. 2*NSEG-1
    const int seg  = bid >> 1;
    const int half = bid & 1;
    const int tid  = threadIdx.x;
    const int lane = tid & 63;
    const int wave = tid >> 6;

    float*    dist    = ws;
    uint32_t* ctrl    = reinterpret_cast<uint32_t*>(reinterpret_cast<char*>(ws) + CTRL_OFF);
    uint32_t* qcnt    = ctrl;                     // stride 16 u32 = 64 B
    uint32_t* ccnt    = ctrl + NSEG * 16;
    float*    partial = reinterpret_cast<float*>(ctrl + (NSEG + 2) * 16);

    // ---------------- phase A: this block's half-segment of dist ----------
    // 16 lanes per point (float4/lane), 32 points per iteration, 8 iters.
    {
        const int sub = tid & 15;
        const int pg  = tid >> 4;   // 0..31
        const float4 cf = reinterpret_cast<const float4*>(center)[seg * 16 + sub];
        const float4* o4 = reinterpret_cast<const float4*>(outputs);
        const int pt_base = half * 256;
        #pragma unroll
        for (int it = 0; it < 8; ++it) {
            const int pt = pt_base + it * 32 + pg;
            float4 v = o4[((size_t)seg * P + pt) * 16 + sub];
            float dx = v.x - cf.x;
            float dy = v.y - cf.y;
            float dz = v.z - cf.z;
            float dw = v.w - cf.w;
            float acc = dx * dx + dy * dy + dz * dz + dw * dw;
            acc += __shfl_xor(acc, 1);
            acc += __shfl_xor(acc, 2);
            acc += __shfl_xor(acc, 4);
            acc += __shfl_xor(acc, 8);
            if (sub == 0) dist[seg * P + pt] = acc;
        }
    }

    // ---- election: second block of this segment to finish runs combine ---
    __syncthreads();                       // all phase-A stores issued
    if (tid == 0) {
        __threadfence();                   // release: dist visible at agent scope
        uint32_t old = __hip_atomic_fetch_add(&qcnt[seg * 16], 1u,
                           __ATOMIC_ACQ_REL, __HIP_MEMORY_SCOPE_AGENT);
        s_flag = (old == 1u);              // counters zeroed by memset each launch
    }
    __syncthreads();
    if (!s_flag) return;                   // uniform per block

    // ---------------- combine (one block per segment) ----------------
    s_lab[tid]  = labels[seg * P + tid];
    s_dist[tid] = dist[seg * P + tid];     // acquire above makes both halves valid
    __syncthreads();

    // ---- per-class first-15 stats; wave w owns class w ----
    {
        const int c = wave;
        float S = 0.0f;
        float M = -INFINITY;
        int taken = 0;   // selected so far (capped at KT)
        int total = 0;   // full class count
        for (int j = 0; j < 8; ++j) {
            const int pos = j * 64 + lane;
            const bool pred = (s_lab[pos] == c);
            const unsigned long long mask = __ballot(pred);
            const int cnt  = __popcll(mask);
            const int rank = __popcll(mask & ((1ull << lane) - 1ull));
            const bool sel = pred && (taken + rank < KT);
            float vs = sel ? s_dist[pos] : 0.0f;
            float vm = sel ? s_dist[pos] : -INFINITY;
            #pragma unroll
            for (int m = 1; m < 64; m <<= 1) {
                vs += __shfl_xor(vs, m);
                vm = fmaxf(vm, __shfl_xor(vm, m));
            }
            S += vs;
            M = fmaxf(M, vm);
            total += cnt;
            taken += cnt;
            if (taken > KT) taken = KT;
        }
        // Rare: fewer than 15 same-class members -> top_k fills with the
        // lowest-index different-class entries (all tied at -inf).
        if (total < KT) {
            const int need = KT - total;
            int t2 = 0;
            for (int j = 0; j < 8 && t2 < need; ++j) {
                const int pos = j * 64 + lane;
                const bool pred = (s_lab[pos] != c);
                const unsigned long long mask = __ballot(pred);
                const int cnt  = __popcll(mask);
                const int rank = __popcll(mask & ((1ull << lane) - 1ull));
                const bool sel = pred && (t2 + rank < need);
                float vs = sel ? s_dist[pos] : 0.0f;
                float vm = sel ? s_dist[pos] : -INFINITY;
                #pragma unroll
                for (int m = 1; m < 64; m <<= 1) {
                    vs += __shfl_xor(vs, m);
                    vm = fmaxf(vm, __shfl_xor(vm, m));
                }
                S += vs;
                M = fmaxf(M, vm);
                t2 += cnt;
                if (t2 > need) t2 = need;
            }
        }
        if (lane == 0) {
            s_S[c]   = S;
            s_M[c]   = M;
            s_cnt[c] = total;
        }
    }
    __syncthreads();

    // ---- combine classes (8 entries) ----
    if (tid == 0) {
        float margin = -INFINITY;
        float pull = 0.0f;
        for (int c = 0; c < NCLS; ++c) {
            if (s_cnt[c] > 0) margin = fmaxf(margin, s_M[c]);
            pull += (float)s_cnt[c] * s_S[c];
            s_hb[c] = 1.0f + s_M[c];
            s_dc[c] = (float)(P - s_cnt[c]);
        }
        s_margin = 1.0f + margin;
        s_pull = pull;
    }
    __syncthreads();

    // ---- push term; one point per thread ----
    {
        const float dv = s_dist[tid];
        const int   c  = s_lab[tid];
        const float h  = fmaxf(s_hb[c] - dv, 0.0f);
        float v = (dv < s_margin) ? s_dc[c] * h : 0.0f;
        #pragma unroll
        for (int m = 1; m < 64; m <<= 1) v += __shfl_xor(v, m);
        if (lane == 0) s_wsum[wave] = v;
    }
    __syncthreads();

    // ---- per-segment total -> partial[seg]; elect the final block ----
    if (tid == 0) {
        float t = s_pull;
        #pragma unroll
        for (int w = 0; w < 8; ++w) t += s_wsum[w];
        partial[seg] = t * (1.0f / ((float)NSEG * (float)P));
        __threadfence();                   // release partial[seg]
        uint32_t old = __hip_atomic_fetch_add(ccnt, 1u,
                           __ATOMIC_ACQ_REL, __HIP_MEMORY_SCOPE_AGENT);
        s_flag = (old == (uint32_t)(NSEG - 1));
    }
    __syncthreads();
    if (!s_flag) return;

    // ---------------- final deterministic reduction (one block) -----------
    if (tid < 64) {
        float v = partial[tid] + partial[tid + 64];
        v += __shfl_xor(v, 1);
        v += __shfl_xor(v, 2);
        v += __shfl_xor(v, 4);
        v += __shfl_xor(v, 8);
        v += __shfl_xor(v, 16);
        v += __shfl_xor(v, 32);
        if (tid == 0) out[0] = v;          // single writer, no pre-zero needed
    }
}

extern "C" void kernel_launch(void* const* d_in, const int* in_sizes, int n_in,
                              void* d_out, int out_size, void* d_ws, size_t ws_size,
                              hipStream_t stream) {
    const float* center  = (const float*)d_in[0];  // (128, 64)
    const float* outputs = (const float*)d_in[1];  // (128, 512, 64)
    const int*   labels  = (const int*)d_in[2];    // (128, 512)
    float* out = (float*)d_out;
    float* ws  = (float*)d_ws;

    // Zero the election counters (8 KB). Graph-capture-safe; makes the
    // fetch_add elections independent of the harness's ws poison pattern.
    hipMemsetAsync((char*)d_ws + CTRL_OFF, 0, CTRL_ZERO_BYTES, stream);
    lmnn_fused<<<dim3(NSEG * 2), dim3(512), 0, stream>>>(center, outputs, labels, ws, out);
}

// Round 2
// 73.175 us; speedup vs baseline: 1.2072x; 1.2072x over previous
//
#include <hip/hip_runtime.h>
#include <math.h>
#include <stdint.h>

constexpr int NSEG = 128;
constexpr int P    = 512;
constexpr int D    = 64;
constexpr int KT   = 15;
constexpr int NCLS = 8;

// Fully block-local fusion: one 1024-thread block per segment computes
// dist into LDS (no global dist array, no fences, no elections), then runs
// the combine phase in-block and plain-stores partial[seg] to ws.
// A trivial 1-block second kernel does the deterministic final sum
// (kernel-boundary ordering provides visibility; this exact butterfly
// produced absmax 0.0 in the previous round).
__global__ __launch_bounds__(1024, 1) void lmnn_seg_kernel(
    const float* __restrict__ center,   // (NSEG, D)
    const float* __restrict__ outputs,  // (NSEG, P, D)
    const int*   __restrict__ labels,   // (NSEG, P)
    float* __restrict__ partial)        // (NSEG,) in d_ws
{
    __shared__ float s_dist[P];
    __shared__ int   s_lab[P];
    __shared__ float s_S[NCLS];
    __shared__ float s_M[NCLS];
    __shared__ int   s_cnt[NCLS];
    __shared__ float s_hb[NCLS];   // 1 + M[c]
    __shared__ float s_dc[NCLS];   // P - cnt[c]
    __shared__ float s_margin;
    __shared__ float s_pull;
    __shared__ float s_wsum[8];

    const int seg  = blockIdx.x;
    const int tid  = threadIdx.x;
    const int lane = tid & 63;
    const int wave = tid >> 6;

    // labels -> LDS (overlaps with the dist loads below)
    if (tid < P) s_lab[tid] = labels[seg * P + tid];

    // ---------------- phase A: dist for the whole segment, in LDS ---------
    // 16 lanes per point (float4/lane); 64 points per iteration; 8 iters.
    // Identical arithmetic/order to the verified dist_kernel.
    {
        const int sub = tid & 15;
        const int pg  = tid >> 4;   // 0..63
        const float4 cf = reinterpret_cast<const float4*>(center)[seg * 16 + sub];
        const float4* o4 = reinterpret_cast<const float4*>(outputs);
        #pragma unroll
        for (int it = 0; it < 8; ++it) {
            const int pt = it * 64 + pg;
            float4 v = o4[((size_t)seg * P + pt) * 16 + sub];
            float dx = v.x - cf.x;
            float dy = v.y - cf.y;
            float dz = v.z - cf.z;
            float dw = v.w - cf.w;
            float acc = dx * dx + dy * dy + dz * dz + dw * dw;
            acc += __shfl_xor(acc, 1);
            acc += __shfl_xor(acc, 2);
            acc += __shfl_xor(acc, 4);
            acc += __shfl_xor(acc, 8);
            if (sub == 0) s_dist[pt] = acc;
        }
    }
    __syncthreads();

    // ---- per-class first-15 stats; wave w (w<8) owns class w ----
    // Sum butterflies kept per-j (bit-identical S); max hoisted out of the
    // j-loop (order-independent -> bit-identical M, half the shuffle chain).
    if (wave < NCLS) {
        const int c = wave;
        float S = 0.0f;
        float vmLane = -INFINITY;   // per-lane running max of selected dists
        int taken = 0;   // selected so far (capped at KT)
        int total = 0;   // full class count
        for (int j = 0; j < 8; ++j) {
            const int pos = j * 64 + lane;
            const bool pred = (s_lab[pos] == c);
            const unsigned long long mask = __ballot(pred);
            const int cnt  = __popcll(mask);
            const int rank = __popcll(mask & ((1ull << lane) - 1ull));
            const bool sel = pred && (taken + rank < KT);
            float vs = sel ? s_dist[pos] : 0.0f;
            if (sel) vmLane = fmaxf(vmLane, s_dist[pos]);
            #pragma unroll
            for (int m = 1; m < 64; m <<= 1) vs += __shfl_xor(vs, m);
            S += vs;
            total += cnt;
            taken += cnt;
            if (taken > KT) taken = KT;
        }
        // Rare: fewer than 15 same-class members -> top_k fills with the
        // lowest-index different-class entries (all tied at -inf).
        if (total < KT) {
            const int need = KT - total;
            int t2 = 0;
            for (int j = 0; j < 8 && t2 < need; ++j) {
                const int pos = j * 64 + lane;
                const bool pred = (s_lab[pos] != c);
                const unsigned long long mask = __ballot(pred);
                const int cnt  = __popcll(mask);
                const int rank = __popcll(mask & ((1ull << lane) - 1ull));
                const bool sel = pred && (t2 + rank < need);
                float vs = sel ? s_dist[pos] : 0.0f;
                if (sel) vmLane = fmaxf(vmLane, s_dist[pos]);
                #pragma unroll
                for (int m = 1; m < 64; m <<= 1) vs += __shfl_xor(vs, m);
                S += vs;
                t2 += cnt;
                if (t2 > need) t2 = need;
            }
        }
        // single 6-step max butterfly over the lane-local maxima
        float M = vmLane;
        #pragma unroll
        for (int m = 1; m < 64; m <<= 1) M = fmaxf(M, __shfl_xor(M, m));
        if (lane == 0) {
            s_S[c]   = S;
            s_M[c]   = M;
            s_cnt[c] = total;
        }
    }
    __syncthreads();

    // ---- combine classes (8 entries) ----
    if (tid == 0) {
        float margin = -INFINITY;
        float pull = 0.0f;
        for (int c = 0; c < NCLS; ++c) {
            if (s_cnt[c] > 0) margin = fmaxf(margin, s_M[c]);
            pull += (float)s_cnt[c] * s_S[c];
            s_hb[c] = 1.0f + s_M[c];
            s_dc[c] = (float)(P - s_cnt[c]);
        }
        s_margin = 1.0f + margin;
        s_pull = pull;
    }
    __syncthreads();

    // ---- push term; one point per thread (threads 0..511) ----
    if (tid < P) {
        const float dv = s_dist[tid];
        const int   c  = s_lab[tid];
        const float h  = fmaxf(s_hb[c] - dv, 0.0f);
        float v = (dv < s_margin) ? s_dc[c] * h : 0.0f;
        #pragma unroll
        for (int m = 1; m < 64; m <<= 1) v += __shfl_xor(v, m);
        if (lane == 0) s_wsum[wave] = v;
    }
    __syncthreads();

    if (tid == 0) {
        float t = s_pull;
        #pragma unroll
        for (int w = 0; w < 8; ++w) t += s_wsum[w];
        partial[seg] = t * (1.0f / ((float)NSEG * (float)P));
    }
}

// Deterministic final sum: 1 block, 64 lanes, single writer of out[0].
// Kernel-boundary ordering on the stream makes partial[] visible.
__global__ __launch_bounds__(64) void final_reduce_kernel(
    const float* __restrict__ partial,  // (NSEG,)
    float* __restrict__ out)
{
    const int tid = threadIdx.x;
    float v = partial[tid] + partial[tid + 64];
    v += __shfl_xor(v, 1);
    v += __shfl_xor(v, 2);
    v += __shfl_xor(v, 4);
    v += __shfl_xor(v, 8);
    v += __shfl_xor(v, 16);
    v += __shfl_xor(v, 32);
    if (tid == 0) out[0] = v;
}

extern "C" void kernel_launch(void* const* d_in, const int* in_sizes, int n_in,
                              void* d_out, int out_size, void* d_ws, size_t ws_size,
                              hipStream_t stream) {
    const float* center  = (const float*)d_in[0];  // (128, 64)
    const float* outputs = (const float*)d_in[1];  // (128, 512, 64)
    const int*   labels  = (const int*)d_in[2];    // (128, 512)
    float* out     = (float*)d_out;
    float* partial = (float*)d_ws;                 // 128 floats

    lmnn_seg_kernel<<<dim3(NSEG), dim3(1024), 0, stream>>>(center, outputs, labels, partial);
    final_reduce_kernel<<<dim3(1), dim3(64), 0, stream>>>(partial, out);
}